// Round 4
// baseline (410.848 us; speedup 1.0000x reference)
//
#include <hip/hip_runtime.h>
#include <hip/hip_bf16.h>

#define BB 32
#define TT 256
#define MM 16
#define DD 128
#define HH 128

typedef unsigned int uint;
typedef unsigned short ushort;

__device__ __forceinline__ float bl16(uint u){ return __uint_as_float(u << 16); }
__device__ __forceinline__ float bh16(uint u){ return __uint_as_float(u & 0xffff0000u); }

__device__ __forceinline__ ushort f2bu(float f){
  __hip_bfloat16 h = __float2bfloat16(f);
  return *(ushort*)&h;
}

__device__ __forceinline__ float hsig(float x){
  return fminf(fmaxf(fmaf(x, 0.2f, 0.5f), 0.0f), 1.0f);
}
__device__ __forceinline__ float tanh_f(float x){
  return 1.0f - 2.0f / (__expf(2.0f * x) + 1.0f);   // saturates correctly
}

// ---------------- K_probe: detect input dtype. flag=1 -> bf16, 0 -> fp32 ------------
// If x is fp32, even-indexed 16-bit halves are low mantissa bits -> mostly "insane"
// as bf16 (~17% pass). If x is bf16, nearly 100% pass.
__global__ void k_probe(const void* __restrict__ xraw, int* __restrict__ flag){
  __shared__ int cnt[64];
  int tid = threadIdx.x;
  const ushort* u = (const ushort*)xraw;
  int c = 0;
  for (int j = 0; j < 32; ++j){
    ushort v = u[2 * (tid * 32 + j)];
    float f = __uint_as_float(((uint)v) << 16);
    if (f == f && fabsf(f) < 64.f && fabsf(f) > 1e-12f) ++c;
  }
  cnt[tid] = c;
  __syncthreads();
  if (tid == 0){
    int s = 0;
    for (int j = 0; j < 64; ++j) s += cnt[j];
    *flag = (s > 1024) ? 1 : 0;
  }
}

// ---------------- K0: v_x[d] = sum_h W_a[d, h]  (h-rows + b_a cancel in softmax) ----
__global__ void k_vx(const void* __restrict__ Wa, const int* __restrict__ flag,
                     float* __restrict__ vx){
  int mode = *flag;
  int d = threadIdx.x;                       // 0..127
  float s = 0.f;
  if (mode){
    const uint4* row = (const uint4*)((const ushort*)Wa + d * HH);
    #pragma unroll
    for (int q = 0; q < 16; ++q){
      uint4 v = row[q];
      s += bl16(v.x) + bh16(v.x) + bl16(v.y) + bh16(v.y)
         + bl16(v.z) + bh16(v.z) + bl16(v.w) + bh16(v.w);
    }
  } else {
    const float4* row = (const float4*)((const float*)Wa + d * HH);
    #pragma unroll
    for (int q = 0; q < 32; ++q){
      float4 v = row[q];
      s += v.x + v.y + v.z + v.w;
    }
  }
  vx[d] = s;
}

// ---------------- K1: per (b,t): softmax over m of x_t·v_x, pool -> new_x (bf16) ----
__global__ __launch_bounds__(128) void k_pool(const void* __restrict__ xraw,
                                              const int* __restrict__ flag,
                                              const float* __restrict__ vx,
                                              __hip_bfloat16* __restrict__ newx){
  __shared__ float xs[MM][DD];     // 8 KB, fp32
  __shared__ float vxs[DD];
  __shared__ float part[128];
  __shared__ float sc[MM];
  int mode = *flag;
  int tid = threadIdx.x;
  int b = blockIdx.x >> 8, t = blockIdx.x & 255;

  float* xdst = &xs[0][0];         // 2048 floats
  if (mode){
    const uint4* s = (const uint4*)((const ushort*)xraw + (size_t)blockIdx.x * 2048);
    #pragma unroll
    for (int q = 0; q < 2; ++q){
      int ch = tid + 128 * q;
      uint4 v = s[ch];
      float* d = &xdst[ch * 8];
      d[0] = bl16(v.x); d[1] = bh16(v.x);
      d[2] = bl16(v.y); d[3] = bh16(v.y);
      d[4] = bl16(v.z); d[5] = bh16(v.z);
      d[6] = bl16(v.w); d[7] = bh16(v.w);
    }
  } else {
    const float4* s = (const float4*)((const float*)xraw + (size_t)blockIdx.x * 2048);
    #pragma unroll
    for (int q = 0; q < 4; ++q){
      int ch = tid + 128 * q;
      *(float4*)&xdst[ch * 4] = s[ch];
    }
  }
  vxs[tid] = vx[tid];
  __syncthreads();

  // scores: thread (m = tid>>3, cc = tid&7) handles 16 d's
  int m = tid >> 3, cc = tid & 7;
  float p = 0.f;
  #pragma unroll
  for (int j = 0; j < 16; ++j)
    p = fmaf(xs[m][cc * 16 + j], vxs[cc * 16 + j], p);
  part[tid] = p;
  __syncthreads();
  if (tid < MM){
    float s = 0.f;
    #pragma unroll
    for (int q = 0; q < 8; ++q) s += part[tid * 8 + q];
    sc[tid] = s;
  }
  __syncthreads();

  // softmax weights (redundant per thread; broadcast LDS reads)
  float mx = sc[0];
  #pragma unroll
  for (int m2 = 1; m2 < MM; ++m2) mx = fmaxf(mx, sc[m2]);
  float wgt[MM]; float den = 0.f;
  #pragma unroll
  for (int m2 = 0; m2 < MM; ++m2){ wgt[m2] = __expf(sc[m2] - mx); den += wgt[m2]; }
  float inv = 1.0f / den;

  // pooled new_x[d], thread = d
  float acc = 0.f;
  #pragma unroll
  for (int m2 = 0; m2 < MM; ++m2)
    acc = fmaf(wgt[m2], xs[m2][tid], acc);
  // layout: row r = t*32 + b
  newx[((size_t)t * BB + b) * DD + tid] = __float2bfloat16(acc * inv);
}

// ---------------- K2: Xp[r, g*128+j] = b_g[j] + sum_d new_x[r,d] * W_g[d,j] ---------
__global__ __launch_bounds__(256) void k_xproj(const __hip_bfloat16* __restrict__ nx,
  const void* __restrict__ W0, const void* __restrict__ W1,
  const void* __restrict__ W2, const void* __restrict__ W3,
  const void* __restrict__ b0_, const void* __restrict__ b1_,
  const void* __restrict__ b2_, const void* __restrict__ b3_,
  const int* __restrict__ flag, float* __restrict__ Xp)
{
  __shared__ __hip_bfloat16 As[128][DD];  // 32 KB
  __shared__ __hip_bfloat16 Ws[DD][HH];   // 32 KB
  int mode = *flag;
  int tid = threadIdx.x;
  int r0 = blockIdx.x * 128;
  int g  = blockIdx.y;
  const void* W  = (g == 0) ? W0  : (g == 1) ? W1  : (g == 2) ? W2  : W3;
  const void* bb = (g == 0) ? b0_ : (g == 1) ? b1_ : (g == 2) ? b2_ : b3_;

  // stage A (always bf16 workspace): 16384 elems = 2048 uint4 chunks
  const uint4* asrc = (const uint4*)(nx + (size_t)r0 * DD);
  uint4* adst = (uint4*)&As[0][0];
  uint4* wdst = (uint4*)&Ws[0][0];
  #pragma unroll
  for (int q = 0; q < 8; ++q) adst[q * 256 + tid] = asrc[q * 256 + tid];

  if (mode){
    const uint4* wsrc = (const uint4*)W;
    #pragma unroll
    for (int q = 0; q < 8; ++q) wdst[q * 256 + tid] = wsrc[q * 256 + tid];
  } else {
    const float4* wsrc = (const float4*)W;
    #pragma unroll
    for (int q = 0; q < 8; ++q){
      int ch = q * 256 + tid;
      float4 a = wsrc[2 * ch], b = wsrc[2 * ch + 1];
      uint4 o;
      o.x = (uint)f2bu(a.x) | ((uint)f2bu(a.y) << 16);
      o.y = (uint)f2bu(a.z) | ((uint)f2bu(a.w) << 16);
      o.z = (uint)f2bu(b.x) | ((uint)f2bu(b.y) << 16);
      o.w = (uint)f2bu(b.z) | ((uint)f2bu(b.w) << 16);
      wdst[ch] = o;
    }
  }
  __syncthreads();

  int ti = tid >> 4, tj = tid & 15;
  int i0 = ti * 8, j0 = tj * 8;
  float acc[8][8] = {};

  for (int k = 0; k < DD; k += 8){
    float a[8][8];                         // [ii][kk]
    #pragma unroll
    for (int ii = 0; ii < 8; ++ii){
      uint4 v = *(const uint4*)&As[i0 + ii][k];
      a[ii][0] = bl16(v.x); a[ii][1] = bh16(v.x);
      a[ii][2] = bl16(v.y); a[ii][3] = bh16(v.y);
      a[ii][4] = bl16(v.z); a[ii][5] = bh16(v.z);
      a[ii][6] = bl16(v.w); a[ii][7] = bh16(v.w);
    }
    #pragma unroll
    for (int kk = 0; kk < 8; ++kk){
      uint4 v = *(const uint4*)&Ws[k + kk][j0];
      float w[8];
      w[0] = bl16(v.x); w[1] = bh16(v.x);
      w[2] = bl16(v.y); w[3] = bh16(v.y);
      w[4] = bl16(v.z); w[5] = bh16(v.z);
      w[6] = bl16(v.w); w[7] = bh16(v.w);
      #pragma unroll
      for (int ii = 0; ii < 8; ++ii)
        #pragma unroll
        for (int jj = 0; jj < 8; ++jj)
          acc[ii][jj] = fmaf(a[ii][kk], w[jj], acc[ii][jj]);
    }
  }

  float bias[8];
  if (mode){
    #pragma unroll
    for (int jj = 0; jj < 8; ++jj)
      bias[jj] = __uint_as_float(((uint)((const ushort*)bb)[j0 + jj]) << 16);
  } else {
    #pragma unroll
    for (int jj = 0; jj < 8; ++jj) bias[jj] = ((const float*)bb)[j0 + jj];
  }
  #pragma unroll
  for (int ii = 0; ii < 8; ++ii){
    size_t r = (size_t)(r0 + i0 + ii);
    float* orow = &Xp[r * 512 + g * HH + j0];
    float4 o1 = make_float4(acc[ii][0] + bias[0], acc[ii][1] + bias[1],
                            acc[ii][2] + bias[2], acc[ii][3] + bias[3]);
    float4 o2 = make_float4(acc[ii][4] + bias[4], acc[ii][5] + bias[5],
                            acc[ii][6] + bias[6], acc[ii][7] + bias[7]);
    *(float4*)orow       = o1;
    *(float4*)(orow + 4) = o2;
  }
}

// ---------------- K3: 32 independent recurrences, one block per batch ---------------
// OUTPUT IS FP32 (reference returns float32) — this was the round-2 failure.
__global__ __launch_bounds__(1024) void k_rec(const float* __restrict__ Xp,
  const void* __restrict__ Ui, const void* __restrict__ Uf,
  const void* __restrict__ Uc, const void* __restrict__ Uo,
  const int* __restrict__ flag, float* __restrict__ out)
{
  __shared__ float hbuf[HH];
  __shared__ float part[1024];
  int mode = *flag;
  int tid = threadIdx.x;
  int b   = blockIdx.x;
  int n   = tid & 511;
  int kc  = tid >> 9;
  int g   = n >> 7, nl = n & 127;
  int lane = tid & 63;
  const void* Ug = (g == 0) ? Ui : (g == 1) ? Uf : (g == 2) ? Uc : Uo;

  float Ureg[64];
  if (mode){
    const ushort* U16 = (const ushort*)Ug;
    #pragma unroll
    for (int q = 0; q < 64; ++q)
      Ureg[q] = __uint_as_float(((uint)U16[(size_t)(kc * 64 + q) * HH + nl]) << 16);
  } else {
    const float* U32 = (const float*)Ug;
    #pragma unroll
    for (int q = 0; q < 64; ++q)
      Ureg[q] = U32[(size_t)(kc * 64 + q) * HH + nl];
  }

  if (tid < HH) hbuf[tid] = 0.f;
  float c = 0.f, h = 0.f;
  __syncthreads();

  for (int t = 0; t < TT; ++t){
    // prefetch this step's x-projection (latency hidden behind k-loop)
    float xpi = 0.f, xpf = 0.f, xpc = 0.f, xpo = 0.f;
    if (tid < HH){
      const float* xr = Xp + ((size_t)t * BB + b) * 512;
      xpi = xr[tid]; xpf = xr[128 + tid]; xpc = xr[256 + tid]; xpo = xr[384 + tid];
    }

    float vh = hbuf[kc * 64 + lane];
    float a0 = 0.f, a1 = 0.f;
    #pragma unroll
    for (int q = 0; q < 64; q += 2){
      float h0 = __uint_as_float((uint)__builtin_amdgcn_readlane((int)__float_as_uint(vh), q));
      float h1 = __uint_as_float((uint)__builtin_amdgcn_readlane((int)__float_as_uint(vh), q + 1));
      a0 = fmaf(h0, Ureg[q],     a0);
      a1 = fmaf(h1, Ureg[q + 1], a1);
    }
    part[tid] = a0 + a1;
    __syncthreads();

    if (tid < HH){
      float pi = part[tid]        + part[512 + tid] + xpi;
      float pf = part[128 + tid]  + part[640 + tid] + xpf;
      float pc = part[256 + tid]  + part[768 + tid] + xpc;
      float po = part[384 + tid]  + part[896 + tid] + xpo;
      float ig = hsig(pi), fg = hsig(pf), og = hsig(po);
      float gg = tanh_f(pc);
      c = fmaf(fg, c, ig * gg);
      h = og * tanh_f(c);
      hbuf[tid] = h;
    }
    __syncthreads();
  }

  if (tid < HH) out[b * HH + tid] = h;   // fp32 store
}

extern "C" void kernel_launch(void* const* d_in, const int* in_sizes, int n_in,
                              void* d_out, int out_size, void* d_ws, size_t ws_size,
                              hipStream_t stream) {
  (void)in_sizes; (void)n_in; (void)out_size; (void)ws_size;

  // ---- workspace layout (~18.9 MB) ----
  // [0,16)       flag
  // [16,528)     vx fp32[128]
  // [1024, +2MB) newx bf16[8192*128]
  // [2098176, +16MB) Xp fp32[8192*512]
  char* ws = (char*)d_ws;
  int* flag = (int*)ws;
  float* vx = (float*)(ws + 16);
  __hip_bfloat16* newx = (__hip_bfloat16*)(ws + 1024);
  float* Xp = (float*)(ws + 1024 + (size_t)2 * 1024 * 1024);

  k_probe<<<1, 64, 0, stream>>>(d_in[0], flag);
  k_vx<<<1, 128, 0, stream>>>(d_in[1], flag, vx);
  k_pool<<<BB * TT, 128, 0, stream>>>(d_in[0], flag, vx, newx);
  dim3 g2(64, 4);
  k_xproj<<<g2, 256, 0, stream>>>(newx,
      d_in[3], d_in[6], d_in[9], d_in[12],     // W_i, W_f, W_c, W_o
      d_in[5], d_in[8], d_in[11], d_in[14],    // b_i, b_f, b_c, b_o
      flag, Xp);
  k_rec<<<BB, 1024, 0, stream>>>(Xp,
      d_in[4], d_in[7], d_in[10], d_in[13],    // U_i, U_f, U_c, U_o
      flag, (float*)d_out);
}

// Round 5
// 330.299 us; speedup vs baseline: 1.2439x; 1.2439x over previous
//
#include <hip/hip_runtime.h>
#include <hip/hip_bf16.h>

#define BB 32
#define TT 256
#define MM 16
#define DD 128
#define HH 128

typedef unsigned int uint;
typedef unsigned short ushort;

__device__ __forceinline__ float bl16(uint u){ return __uint_as_float(u << 16); }
__device__ __forceinline__ float bh16(uint u){ return __uint_as_float(u & 0xffff0000u); }

__device__ __forceinline__ ushort f2bu(float f){
  __hip_bfloat16 h = __float2bfloat16(f);
  return *(ushort*)&h;
}

__device__ __forceinline__ float hsig(float x){
  return fminf(fmaxf(fmaf(x, 0.2f, 0.5f), 0.0f), 1.0f);
}
__device__ __forceinline__ float tanh_f(float x){
  return 1.0f - 2.0f / (__expf(2.0f * x) + 1.0f);   // saturates correctly
}

// ---------------- K_init: dtype probe (flag=1 bf16, 0 fp32) + v_x[d] = sum_h W_a[d,h]
__global__ __launch_bounds__(128) void k_init(const void* __restrict__ xraw,
                                              const void* __restrict__ Wa,
                                              int* __restrict__ flag,
                                              float* __restrict__ vx){
  __shared__ int cnt[128];
  __shared__ int smode;
  int tid = threadIdx.x;
  // probe: if fp32, even-indexed 16-bit halves are mantissa garbage (~17% "sane")
  const ushort* u = (const ushort*)xraw;
  int c = 0;
  for (int j = 0; j < 16; ++j){
    ushort v = u[2 * (tid * 16 + j)];
    float f = __uint_as_float(((uint)v) << 16);
    if (f == f && fabsf(f) < 64.f && fabsf(f) > 1e-12f) ++c;
  }
  cnt[tid] = c;
  __syncthreads();
  if (tid == 0){
    int s = 0;
    for (int j = 0; j < 128; ++j) s += cnt[j];
    int m = (s > 1024) ? 1 : 0;
    smode = m; *flag = m;
  }
  __syncthreads();
  int mode = smode;

  int d = tid;
  float s = 0.f;
  if (mode){
    const uint4* row = (const uint4*)((const ushort*)Wa + d * HH);
    #pragma unroll
    for (int q = 0; q < 16; ++q){
      uint4 v = row[q];
      s += bl16(v.x) + bh16(v.x) + bl16(v.y) + bh16(v.y)
         + bl16(v.z) + bh16(v.z) + bl16(v.w) + bh16(v.w);
    }
  } else {
    const float4* row = (const float4*)((const float*)Wa + d * HH);
    #pragma unroll
    for (int q = 0; q < 32; ++q){
      float4 v = row[q];
      s += v.x + v.y + v.z + v.w;
    }
  }
  vx[d] = s;
}

// ---------------- K1: per (b,t): softmax over m of x_t·v_x, pool -> new_x (bf16) ----
__global__ __launch_bounds__(128) void k_pool(const void* __restrict__ xraw,
                                              const int* __restrict__ flag,
                                              const float* __restrict__ vx,
                                              __hip_bfloat16* __restrict__ newx){
  __shared__ float xs[MM][DD];     // 8 KB, fp32
  __shared__ float vxs[DD];
  __shared__ float part[128];
  __shared__ float sc[MM];
  int mode = *flag;
  int tid = threadIdx.x;
  int b = blockIdx.x >> 8, t = blockIdx.x & 255;

  float* xdst = &xs[0][0];         // 2048 floats
  if (mode){
    const uint4* s = (const uint4*)((const ushort*)xraw + (size_t)blockIdx.x * 2048);
    #pragma unroll
    for (int q = 0; q < 2; ++q){
      int ch = tid + 128 * q;
      uint4 v = s[ch];
      float* d = &xdst[ch * 8];
      d[0] = bl16(v.x); d[1] = bh16(v.x);
      d[2] = bl16(v.y); d[3] = bh16(v.y);
      d[4] = bl16(v.z); d[5] = bh16(v.z);
      d[6] = bl16(v.w); d[7] = bh16(v.w);
    }
  } else {
    const float4* s = (const float4*)((const float*)xraw + (size_t)blockIdx.x * 2048);
    #pragma unroll
    for (int q = 0; q < 4; ++q){
      int ch = tid + 128 * q;
      *(float4*)&xdst[ch * 4] = s[ch];
    }
  }
  vxs[tid] = vx[tid];
  __syncthreads();

  // scores: thread (m = tid>>3, cc = tid&7) handles 16 d's
  int m = tid >> 3, cc = tid & 7;
  float p = 0.f;
  #pragma unroll
  for (int j = 0; j < 16; ++j)
    p = fmaf(xs[m][cc * 16 + j], vxs[cc * 16 + j], p);
  part[tid] = p;
  __syncthreads();
  if (tid < MM){
    float s = 0.f;
    #pragma unroll
    for (int q = 0; q < 8; ++q) s += part[tid * 8 + q];
    sc[tid] = s;
  }
  __syncthreads();

  float mx = sc[0];
  #pragma unroll
  for (int m2 = 1; m2 < MM; ++m2) mx = fmaxf(mx, sc[m2]);
  float wgt[MM]; float den = 0.f;
  #pragma unroll
  for (int m2 = 0; m2 < MM; ++m2){ wgt[m2] = __expf(sc[m2] - mx); den += wgt[m2]; }
  float inv = 1.0f / den;

  float acc = 0.f;
  #pragma unroll
  for (int m2 = 0; m2 < MM; ++m2)
    acc = fmaf(wgt[m2], xs[m2][tid], acc);
  newx[((size_t)t * BB + b) * DD + tid] = __float2bfloat16(acc * inv);
}

// ---------------- K2: Xp[r, g*128+j] = b_g[j] + sum_d new_x[r,d] * W_g[d,j] ---------
__global__ __launch_bounds__(256) void k_xproj(const __hip_bfloat16* __restrict__ nx,
  const void* __restrict__ W0, const void* __restrict__ W1,
  const void* __restrict__ W2, const void* __restrict__ W3,
  const void* __restrict__ b0_, const void* __restrict__ b1_,
  const void* __restrict__ b2_, const void* __restrict__ b3_,
  const int* __restrict__ flag, float* __restrict__ Xp)
{
  __shared__ __hip_bfloat16 As[128][DD];  // 32 KB
  __shared__ __hip_bfloat16 Ws[DD][HH];   // 32 KB
  int mode = *flag;
  int tid = threadIdx.x;
  int r0 = blockIdx.x * 128;
  int g  = blockIdx.y;
  const void* W  = (g == 0) ? W0  : (g == 1) ? W1  : (g == 2) ? W2  : W3;
  const void* bb = (g == 0) ? b0_ : (g == 1) ? b1_ : (g == 2) ? b2_ : b3_;

  const uint4* asrc = (const uint4*)(nx + (size_t)r0 * DD);
  uint4* adst = (uint4*)&As[0][0];
  uint4* wdst = (uint4*)&Ws[0][0];
  #pragma unroll
  for (int q = 0; q < 8; ++q) adst[q * 256 + tid] = asrc[q * 256 + tid];

  if (mode){
    const uint4* wsrc = (const uint4*)W;
    #pragma unroll
    for (int q = 0; q < 8; ++q) wdst[q * 256 + tid] = wsrc[q * 256 + tid];
  } else {
    const float4* wsrc = (const float4*)W;
    #pragma unroll
    for (int q = 0; q < 8; ++q){
      int ch = q * 256 + tid;
      float4 a = wsrc[2 * ch], b = wsrc[2 * ch + 1];
      uint4 o;
      o.x = (uint)f2bu(a.x) | ((uint)f2bu(a.y) << 16);
      o.y = (uint)f2bu(a.z) | ((uint)f2bu(a.w) << 16);
      o.z = (uint)f2bu(b.x) | ((uint)f2bu(b.y) << 16);
      o.w = (uint)f2bu(b.z) | ((uint)f2bu(b.w) << 16);
      wdst[ch] = o;
    }
  }
  __syncthreads();

  int ti = tid >> 4, tj = tid & 15;
  int i0 = ti * 8, j0 = tj * 8;
  float acc[8][8] = {};

  for (int k = 0; k < DD; k += 8){
    float a[8][8];
    #pragma unroll
    for (int ii = 0; ii < 8; ++ii){
      uint4 v = *(const uint4*)&As[i0 + ii][k];
      a[ii][0] = bl16(v.x); a[ii][1] = bh16(v.x);
      a[ii][2] = bl16(v.y); a[ii][3] = bh16(v.y);
      a[ii][4] = bl16(v.z); a[ii][5] = bh16(v.z);
      a[ii][6] = bl16(v.w); a[ii][7] = bh16(v.w);
    }
    #pragma unroll
    for (int kk = 0; kk < 8; ++kk){
      uint4 v = *(const uint4*)&Ws[k + kk][j0];
      float w[8];
      w[0] = bl16(v.x); w[1] = bh16(v.x);
      w[2] = bl16(v.y); w[3] = bh16(v.y);
      w[4] = bl16(v.z); w[5] = bh16(v.z);
      w[6] = bl16(v.w); w[7] = bh16(v.w);
      #pragma unroll
      for (int ii = 0; ii < 8; ++ii)
        #pragma unroll
        for (int jj = 0; jj < 8; ++jj)
          acc[ii][jj] = fmaf(a[ii][kk], w[jj], acc[ii][jj]);
    }
  }

  float bias[8];
  if (mode){
    #pragma unroll
    for (int jj = 0; jj < 8; ++jj)
      bias[jj] = __uint_as_float(((uint)((const ushort*)bb)[j0 + jj]) << 16);
  } else {
    #pragma unroll
    for (int jj = 0; jj < 8; ++jj) bias[jj] = ((const float*)bb)[j0 + jj];
  }
  #pragma unroll
  for (int ii = 0; ii < 8; ++ii){
    size_t r = (size_t)(r0 + i0 + ii);
    float* orow = &Xp[r * 512 + g * HH + j0];
    float4 o1 = make_float4(acc[ii][0] + bias[0], acc[ii][1] + bias[1],
                            acc[ii][2] + bias[2], acc[ii][3] + bias[3]);
    float4 o2 = make_float4(acc[ii][4] + bias[4], acc[ii][5] + bias[5],
                            acc[ii][6] + bias[6], acc[ii][7] + bias[7]);
    *(float4*)orow       = o1;
    *(float4*)(orow + 4) = o2;
  }
}

// ---------------- K3: recurrence, 32 blocks x 512 threads, ONE barrier per step -----
// thread: kc = tid>>7 (k-quarter, 32 k's), oc = tid&127 (4 adjacent output cols
// n0=4*oc..+3, all in gate g = n0>>7). After the barrier EVERY thread redundantly
// computes the gate update for j0 = kc*32+(lane&31) (4x redundant) so next step's
// h value (vh) is in-register -> no hbuf, no second barrier. part[] double-buffered.
__global__ __launch_bounds__(512) void k_rec(const float* __restrict__ Xp,
  const void* __restrict__ Ui, const void* __restrict__ Uf,
  const void* __restrict__ Uc, const void* __restrict__ Uo,
  const int* __restrict__ flag, float* __restrict__ out)
{
  __shared__ float part[2][4][512];   // 16 KB, [parity][kc][n]
  int mode = *flag;
  int tid = threadIdx.x;
  int b   = blockIdx.x;
  int kc  = tid >> 7;                 // 0..3
  int oc  = tid & 127;
  int n0  = oc * 4;                   // 4 cols, same gate
  int g   = n0 >> 7, c0 = n0 & 127;
  int lane = tid & 63;
  int j0  = kc * 32 + (lane & 31);    // gate index this thread redundantly owns
  const void* Ug = (g == 0) ? Ui : (g == 1) ? Uf : (g == 2) ? Uc : Uo;

  // U fragment: U[k][c0..c0+3] for k = kc*32 + q
  float U0[32], U1[32], U2[32], U3[32];
  if (mode){
    const ushort* U16 = (const ushort*)Ug;
    #pragma unroll
    for (int q = 0; q < 32; ++q){
      const ushort* p = &U16[(size_t)(kc * 32 + q) * HH + c0];
      uint2 v = *(const uint2*)p;
      U0[q] = bl16(v.x); U1[q] = bh16(v.x);
      U2[q] = bl16(v.y); U3[q] = bh16(v.y);
    }
  } else {
    const float* U32 = (const float*)Ug;
    #pragma unroll
    for (int q = 0; q < 32; ++q){
      float4 v = *(const float4*)&U32[(size_t)(kc * 32 + q) * HH + c0];
      U0[q] = v.x; U1[q] = v.y; U2[q] = v.z; U3[q] = v.w;
    }
  }

  float vh = 0.f, cst = 0.f;
  // prefetch step 0's x-projection for j0
  const float* xr0 = Xp + (size_t)b * 512;
  float xi = xr0[j0], xf = xr0[128 + j0], xc = xr0[256 + j0], xo = xr0[384 + j0];

  for (int t = 0; t < TT; ++t){
    // prefetch next step (clamped; covered by k-loop latency)
    int tn = (t + 1 < TT) ? t + 1 : t;
    const float* xr = Xp + ((size_t)tn * BB + b) * 512;
    float nxi = xr[j0], nxf = xr[128 + j0], nxc = xr[256 + j0], nxo = xr[384 + j0];

    // k-loop: 32 readlane broadcasts amortized over 4 output columns
    float a0 = 0.f, a1 = 0.f, a2 = 0.f, a3 = 0.f;
    #pragma unroll
    for (int q = 0; q < 32; ++q){
      float hq = __uint_as_float((uint)__builtin_amdgcn_readlane((int)__float_as_uint(vh), q));
      a0 = fmaf(hq, U0[q], a0);
      a1 = fmaf(hq, U1[q], a1);
      a2 = fmaf(hq, U2[q], a2);
      a3 = fmaf(hq, U3[q], a3);
    }
    int par = t & 1;
    *(float4*)&part[par][kc][n0] = make_float4(a0, a1, a2, a3);
    __syncthreads();

    // redundant gate update for j0 (4 threads share each j0)
    float pi = part[par][0][j0]       + part[par][1][j0]       + part[par][2][j0]       + part[par][3][j0]       + xi;
    float pf = part[par][0][128 + j0] + part[par][1][128 + j0] + part[par][2][128 + j0] + part[par][3][128 + j0] + xf;
    float pc = part[par][0][256 + j0] + part[par][1][256 + j0] + part[par][2][256 + j0] + part[par][3][256 + j0] + xc;
    float po = part[par][0][384 + j0] + part[par][1][384 + j0] + part[par][2][384 + j0] + part[par][3][384 + j0] + xo;
    float ig = hsig(pi), fg = hsig(pf), og = hsig(po);
    float gg = tanh_f(pc);
    cst = fmaf(fg, cst, ig * gg);
    vh  = og * tanh_f(cst);
    xi = nxi; xf = nxf; xc = nxc; xo = nxo;
  }

  // one writer per j0: first wave of each kc, lanes 0..31
  if (((tid >> 6) & 1) == 0 && (lane & 32) == 0)
    out[b * HH + j0] = vh;
}

extern "C" void kernel_launch(void* const* d_in, const int* in_sizes, int n_in,
                              void* d_out, int out_size, void* d_ws, size_t ws_size,
                              hipStream_t stream) {
  (void)in_sizes; (void)n_in; (void)out_size; (void)ws_size;

  // ---- workspace layout (~18.9 MB) ----
  char* ws = (char*)d_ws;
  int* flag = (int*)ws;
  float* vx = (float*)(ws + 16);
  __hip_bfloat16* newx = (__hip_bfloat16*)(ws + 1024);
  float* Xp = (float*)(ws + 1024 + (size_t)2 * 1024 * 1024);

  k_init<<<1, 128, 0, stream>>>(d_in[0], d_in[1], flag, vx);
  k_pool<<<BB * TT, 128, 0, stream>>>(d_in[0], flag, vx, newx);
  dim3 g2(64, 4);
  k_xproj<<<g2, 256, 0, stream>>>(newx,
      d_in[3], d_in[6], d_in[9], d_in[12],     // W_i, W_f, W_c, W_o
      d_in[5], d_in[8], d_in[11], d_in[14],    // b_i, b_f, b_c, b_o
      flag, Xp);
  k_rec<<<BB, 512, 0, stream>>>(Xp,
      d_in[4], d_in[7], d_in[10], d_in[13],    // U_i, U_f, U_c, U_o
      flag, (float*)d_out);
}